// Round 3
// baseline (175.474 us; speedup 1.0000x reference)
//
#include <hip/hip_runtime.h>
#include <hip/hip_bf16.h>

// B=8, C=64, N=4096, CQK=8. Flash-attention formulation with FIXED softmax offset:
//   s_out = log2e * (f.g) - 28.84  (offset baked into MFMA k=8 slot; cancels in norm)
//   p = exp2(s_out); beta = p / sum_n p; o = gamma*hv@beta + x
// ws: ft_ext [B][N][16] bf16 (cols 0..7 = log2e*f, col 8 = 1.0, 9..15 = 0),
//     gt [B][N][8] bf16, hv [B][64][N] bf16.

typedef __attribute__((ext_vector_type(16))) float f32x16;
typedef __attribute__((ext_vector_type(8))) short bf16x8;

#if __has_builtin(__builtin_amdgcn_exp2f)
#define EXP2(x) __builtin_amdgcn_exp2f(x)
#else
#define EXP2(x) exp2f(x)
#endif

__device__ __forceinline__ unsigned pk_bf16(float lo, float hi) {
  union { __hip_bfloat16 h; unsigned short u; } a, b;
  a.h = __float2bfloat16(lo); b.h = __float2bfloat16(hi);
  return (unsigned)a.u | ((unsigned)b.u << 16);
}

__device__ __forceinline__ void plane32_swap(unsigned& a, unsigned& b) {
  asm("v_permlane32_swap_b32 %0, %1" : "+v"(a), "+v"(b));
}

// ---------------- projection: f, g, hv from x ----------------
__global__ __launch_bounds__(512) void proj_kernel(
    const float* __restrict__ x,
    const float* __restrict__ Wq, const float* __restrict__ bq,
    const float* __restrict__ Wk, const float* __restrict__ bk,
    const float* __restrict__ Wv, const float* __restrict__ bv,
    __hip_bfloat16* __restrict__ ft,
    __hip_bfloat16* __restrict__ gt,
    __hip_bfloat16* __restrict__ hv) {
  __shared__ float xs[64][65];
  const int t = threadIdx.x;
  const int p = t & 63;
  const int grp = t >> 6;  // 0..7, wave-uniform
  const int b = blockIdx.x >> 6;
  const int n0 = (blockIdx.x & 63) << 6;

#pragma unroll
  for (int r = 0; r < 8; ++r) {
    const int c = grp * 8 + r;
    xs[c][p] = x[(b * 64 + c) * 4096 + n0 + p];
  }
  __syncthreads();

  float xcol[64];
#pragma unroll
  for (int c = 0; c < 64; ++c) xcol[c] = xs[c][p];

  const int o0 = __builtin_amdgcn_readfirstlane(grp);
  const int n = n0 + p;

  {
    float aq = bq[o0], ag = bk[o0];
#pragma unroll
    for (int c = 0; c < 64; ++c) {
      aq = fmaf(Wq[o0 * 64 + c], xcol[c], aq);
      ag = fmaf(Wk[o0 * 64 + c], xcol[c], ag);
    }
    ft[(b * 4096 + n) * 16 + o0] = __float2bfloat16(aq * 1.44269504f);  // log2e * f
    gt[(b * 4096 + n) * 8 + o0] = __float2bfloat16(ag);
  }
  if (o0 == 0) {  // bias columns k=8..15 of ft_ext: {1.0bf16, 0,...}
    const bf16x8 fb = {(short)0x3F80, 0, 0, 0, 0, 0, 0, 0};
    *(bf16x8*)(ft + (b * 4096 + n) * 16 + 8) = fb;
  }
#pragma unroll
  for (int k = 0; k < 8; ++k) {
    const int o = o0 + 8 * k;
    float av = bv[o];
#pragma unroll
    for (int c = 0; c < 64; ++c) av = fmaf(Wv[o * 64 + c], xcol[c], av);
    hv[(b * 64 + o) * 4096 + n] = __float2bfloat16(av);
  }
}

// ---------------- fused flash attention, fixed-offset softmax ----------------
// Block = (batch, 32-query tile); 8 waves, wave wv handles keys [wv*512, wv*512+512).
// QK: mfma_32x32x16(A=ft_ext tile, B=g padded with k=8 offset slot).
//   D: col m=l&31, row n=(j&3)+8*(j>>2)+4*(l>>5)  [verified m74/m101; r2 passed on HW]
// P redistribution to PV B-frag via v_permlane32_swap_b32; PV over 64 channels.
__global__ __launch_bounds__(512, 8) void attn_kernel(
    const __hip_bfloat16* __restrict__ ft,
    const __hip_bfloat16* __restrict__ gt,
    const __hip_bfloat16* __restrict__ hv,
    const float* __restrict__ x,
    const float* __restrict__ gamma,
    float* __restrict__ out) {
  __shared__ float lacc[8][16][64];  // 32 KB, reused for acc0 then acc1
  __shared__ float lL[8][64];        // 2 KB

  const int wv = threadIdx.x >> 6;   // 0..7
  const int l = threadIdx.x & 63;
  const int hi = l >> 5;
  const int lm = l & 31;
  const int b = blockIdx.x >> 7;          // 128 query tiles per batch
  const int m0 = (blockIdx.x & 127) << 5;

  const __hip_bfloat16* ftb = ft + b * 4096 * 16;
  const __hip_bfloat16* gtb = gt + b * 4096 * 8;
  const __hip_bfloat16* hb = hv + b * 64 * 4096;

  f32x16 zf16;
#pragma unroll
  for (int j = 0; j < 16; ++j) zf16[j] = 0.f;

  // Q fragment (B operand): lanes<32 carry k=0..7 (=q); lanes>=32 carry k=8 offset
  bf16x8 gf = {(short)0xC1E7, 0, 0, 0, 0, 0, 0, 0};  // -28.84 at k=8
  if (l < 32) gf = *(const bf16x8*)(gtb + (m0 + lm) * 8);

  f32x16 acc0 = zf16, acc1 = zf16;
  float Lsum = 0.f;

  for (int it = 0; it < 16; ++it) {
    const int n0 = (wv << 9) + (it << 5);

    // A-frag: row n=lm, k=hi*8+e — contiguous 1KB block across the wave
    const bf16x8 af = *(const bf16x8*)(ftb + (n0 + lm) * 16 + hi * 8);
    const f32x16 s = __builtin_amdgcn_mfma_f32_32x32x16_bf16(af, gf, zf16, 0, 0, 0);

    // p = exp2(s_out) directly; no max tracking, no rescale
    float rs = 0.f;
    unsigned w[8];
#pragma unroll
    for (int j = 0; j < 8; ++j) {
      const float pa = EXP2(s[2 * j]);
      const float pc = EXP2(s[2 * j + 1]);
      rs += pa + pc;
      w[j] = pk_bf16(pa, pc);
    }
    Lsum += rs;

    // redistribute into PV B-fragment k-order (same mapping as r2, HW-verified)
    plane32_swap(w[0], w[2]);
    plane32_swap(w[1], w[3]);
    plane32_swap(w[4], w[6]);
    plane32_swap(w[5], w[7]);
    union { unsigned u[4]; bf16x8 v; } pb0, pb1;
    pb0.u[0] = w[0]; pb0.u[1] = w[1]; pb0.u[2] = w[2]; pb0.u[3] = w[3];
    pb1.u[0] = w[4]; pb1.u[1] = w[5]; pb1.u[2] = w[6]; pb1.u[3] = w[7];

    const __hip_bfloat16* hp = hb + n0 + hi * 8;
    {
      const bf16x8 va0 = *(const bf16x8*)(hp + lm * 4096);
      const bf16x8 va1 = *(const bf16x8*)(hp + lm * 4096 + 16);
      acc0 = __builtin_amdgcn_mfma_f32_32x32x16_bf16(va0, pb0.v, acc0, 0, 0, 0);
      acc0 = __builtin_amdgcn_mfma_f32_32x32x16_bf16(va1, pb1.v, acc0, 0, 0, 0);
    }
    {
      const bf16x8 va2 = *(const bf16x8*)(hp + (32 + lm) * 4096);
      const bf16x8 va3 = *(const bf16x8*)(hp + (32 + lm) * 4096 + 16);
      acc1 = __builtin_amdgcn_mfma_f32_32x32x16_bf16(va2, pb0.v, acc1, 0, 0, 0);
      acc1 = __builtin_amdgcn_mfma_f32_32x32x16_bf16(va3, pb1.v, acc1, 0, 0, 0);
    }
  }

  // ---- cross-wave combine, 2-phase to halve LDS ----
  const float Lfull = Lsum + __shfl_xor(Lsum, 32);
  lL[wv][l] = Lfull;
#pragma unroll
  for (int j = 0; j < 16; ++j) lacc[wv][j][l] = acc0[j];
  __syncthreads();

  float Lg = 0.f;
#pragma unroll
  for (int ww = 0; ww < 8; ++ww) Lg += lL[ww][l];
  const float scale = gamma[0] / Lg;

  const float* xb = x + b * 64 * 4096;
  float* ob = out + b * 64 * 4096;

#pragma unroll
  for (int r = 0; r < 2; ++r) {  // phase A: acc0 rows, channels 0..31
    const int j = wv * 2 + r;
    float v = 0.f;
#pragma unroll
    for (int ww = 0; ww < 8; ++ww) v += lacc[ww][j][l];
    const int c = (j & 3) + 8 * (j >> 2) + 4 * hi;
    const int idx = c * 4096 + m0 + lm;
    ob[idx] = fmaf(v, scale, xb[idx]);
  }
  __syncthreads();
#pragma unroll
  for (int j = 0; j < 16; ++j) lacc[wv][j][l] = acc1[j];
  __syncthreads();
#pragma unroll
  for (int r = 0; r < 2; ++r) {  // phase B: acc1 rows, channels 32..63
    const int j = wv * 2 + r;
    float v = 0.f;
#pragma unroll
    for (int ww = 0; ww < 8; ++ww) v += lacc[ww][j][l];
    const int c = 32 + (j & 3) + 8 * (j >> 2) + 4 * hi;
    const int idx = c * 4096 + m0 + lm;
    ob[idx] = fmaf(v, scale, xb[idx]);
  }
}

extern "C" void kernel_launch(void* const* d_in, const int* in_sizes, int n_in,
                              void* d_out, int out_size, void* d_ws, size_t ws_size,
                              hipStream_t stream) {
  const float* x = (const float*)d_in[0];
  const float* Wq = (const float*)d_in[1];
  const float* bq = (const float*)d_in[2];
  const float* Wk = (const float*)d_in[3];
  const float* bk = (const float*)d_in[4];
  const float* Wv = (const float*)d_in[5];
  const float* bv = (const float*)d_in[6];
  const float* gamma = (const float*)d_in[7];
  float* out = (float*)d_out;

  __hip_bfloat16* ft = (__hip_bfloat16*)d_ws;          // [8][4096][16] (ext, 1 MB)
  __hip_bfloat16* gt = ft + 8 * 4096 * 16;             // [8][4096][8]  (0.5 MB)
  __hip_bfloat16* hv = gt + 8 * 4096 * 8;              // [8][64][4096] (4 MB)

  hipLaunchKernelGGL(proj_kernel, dim3(512), dim3(512), 0, stream,
                     x, Wq, bq, Wk, bk, Wv, bv, ft, gt, hv);
  hipLaunchKernelGGL(attn_kernel, dim3(1024), dim3(512), 0, stream,
                     ft, gt, hv, x, gamma, out);
}

// Round 10
// 149.332 us; speedup vs baseline: 1.1751x; 1.1751x over previous
//
#include <hip/hip_runtime.h>
#include <hip/hip_bf16.h>

// B=8, C=64, N=4096, CQK=8. Flash-attention formulation with FIXED softmax offset:
//   s_out = log2e * (f.g) - 28.84  (offset baked into MFMA k=8 slot; cancels in norm)
//   p = exp2(s_out); beta = p / sum_n p; o = gamma*hv@beta + x
// ws: ft_ext [B][N][16] bf16 (cols 0..7 = log2e*f, col 8 = 1.0, 9..15 = 0),
//     gt [B][N][8] bf16, hv [B][64][N] bf16.

typedef __attribute__((ext_vector_type(16))) float f32x16;
typedef __attribute__((ext_vector_type(8))) short bf16x8;

#if __has_builtin(__builtin_amdgcn_exp2f)
#define EXP2(x) __builtin_amdgcn_exp2f(x)
#else
#define EXP2(x) exp2f(x)
#endif

__device__ __forceinline__ unsigned pk_bf16(float lo, float hi) {
  union { __hip_bfloat16 h; unsigned short u; } a, b;
  a.h = __float2bfloat16(lo); b.h = __float2bfloat16(hi);
  return (unsigned)a.u | ((unsigned)b.u << 16);
}

__device__ __forceinline__ void plane32_swap(unsigned& a, unsigned& b) {
  asm("v_permlane32_swap_b32 %0, %1" : "+v"(a), "+v"(b));
}

// ---------------- projection: f, g, hv from x ----------------
__global__ __launch_bounds__(512) void proj_kernel(
    const float* __restrict__ x,
    const float* __restrict__ Wq, const float* __restrict__ bq,
    const float* __restrict__ Wk, const float* __restrict__ bk,
    const float* __restrict__ Wv, const float* __restrict__ bv,
    __hip_bfloat16* __restrict__ ft,
    __hip_bfloat16* __restrict__ gt,
    __hip_bfloat16* __restrict__ hv) {
  __shared__ float xs[64][65];
  const int t = threadIdx.x;
  const int p = t & 63;
  const int grp = t >> 6;  // 0..7, wave-uniform
  const int b = blockIdx.x >> 6;
  const int n0 = (blockIdx.x & 63) << 6;

#pragma unroll
  for (int r = 0; r < 8; ++r) {
    const int c = grp * 8 + r;
    xs[c][p] = x[(b * 64 + c) * 4096 + n0 + p];
  }
  __syncthreads();

  float xcol[64];
#pragma unroll
  for (int c = 0; c < 64; ++c) xcol[c] = xs[c][p];

  const int o0 = __builtin_amdgcn_readfirstlane(grp);
  const int n = n0 + p;

  {
    float aq = bq[o0], ag = bk[o0];
#pragma unroll
    for (int c = 0; c < 64; ++c) {
      aq = fmaf(Wq[o0 * 64 + c], xcol[c], aq);
      ag = fmaf(Wk[o0 * 64 + c], xcol[c], ag);
    }
    ft[(b * 4096 + n) * 16 + o0] = __float2bfloat16(aq * 1.44269504f);  // log2e * f
    gt[(b * 4096 + n) * 8 + o0] = __float2bfloat16(ag);
  }
  if (o0 == 0) {  // bias columns k=8..15 of ft_ext: {1.0bf16, 0,...}
    const bf16x8 fb = {(short)0x3F80, 0, 0, 0, 0, 0, 0, 0};
    *(bf16x8*)(ft + (b * 4096 + n) * 16 + 8) = fb;
  }
#pragma unroll
  for (int k = 0; k < 8; ++k) {
    const int o = o0 + 8 * k;
    float av = bv[o];
#pragma unroll
    for (int c = 0; c < 64; ++c) av = fmaf(Wv[o * 64 + c], xcol[c], av);
    hv[(b * 64 + o) * 4096 + n] = __float2bfloat16(av);
  }
}

// ---------------- fused flash attention, fixed-offset softmax + prefetch ----------------
// Block = (batch, 32-query tile); 4 waves, wave wv handles keys [wv*1024, +1024), 32 iters.
// QK: mfma_32x32x16(A=ft_ext rows, B=g with k=8 offset slot).
//   D: col m=l&31, row n=(j&3)+8*(j>>2)+4*(l>>5)  [HW-verified r2/r3]
// Depth-1 prefetch of {af, va0, va1}; va2/va3 issued at iter top (covered by softmax).
// XCD swizzle: batch == XCD -> per-XCD L2 working set 0.64 MB.
__global__ __launch_bounds__(256, 3) void attn_kernel(
    const __hip_bfloat16* __restrict__ ft,
    const __hip_bfloat16* __restrict__ gt,
    const __hip_bfloat16* __restrict__ hv,
    const float* __restrict__ x,
    const float* __restrict__ gamma,
    float* __restrict__ out) {
  __shared__ float lacc[4][16][64];  // 16 KB, reused acc0 then acc1
  __shared__ float lL[4][64];        // 1 KB

  const int wv = threadIdx.x >> 6;   // 0..3
  const int l = threadIdx.x & 63;
  const int hi = l >> 5;
  const int lm = l & 31;
  const int bid = blockIdx.x;
  const int swz = ((bid & 7) << 7) + (bid >> 3);  // bijective: 1024 % 8 == 0
  const int b = swz >> 7;                          // batch == XCD
  const int m0 = (swz & 127) << 5;

  const __hip_bfloat16* ftb = ft + b * 4096 * 16;
  const __hip_bfloat16* gtb = gt + b * 4096 * 8;
  const __hip_bfloat16* hb = hv + b * 64 * 4096;

  f32x16 zf16;
#pragma unroll
  for (int j = 0; j < 16; ++j) zf16[j] = 0.f;

  // Q fragment (B operand): lanes<32 carry k=0..7 (=q); lanes>=32 carry k=8 offset
  bf16x8 gf = {(short)0xC1E7, 0, 0, 0, 0, 0, 0, 0};  // -28.84 at k=8
  if (l < 32) gf = *(const bf16x8*)(gtb + (m0 + lm) * 8);

  f32x16 acc0 = zf16, acc1 = zf16;
  float Lsum = 0.f;

  const int kb = wv << 10;  // wave key base
  // preload it=0
  bf16x8 af_c = *(const bf16x8*)(ftb + (kb + lm) * 16 + hi * 8);
  bf16x8 va0_c = *(const bf16x8*)(hb + kb + hi * 8 + lm * 4096);
  bf16x8 va1_c = *(const bf16x8*)(hb + kb + hi * 8 + lm * 4096 + 16);

  for (int it = 0; it < 32; ++it) {
    const int n0c = kb + (it << 5);
    const int n0n = kb + (((it + 1) & 31) << 5);

    // current-iter late operands (latency covered by QK+softmax below)
    const bf16x8 va2_c = *(const bf16x8*)(hb + n0c + hi * 8 + (32 + lm) * 4096);
    const bf16x8 va3_c = *(const bf16x8*)(hb + n0c + hi * 8 + (32 + lm) * 4096 + 16);
    // next-iter prefetch
    const bf16x8 af_n = *(const bf16x8*)(ftb + (n0n + lm) * 16 + hi * 8);
    const bf16x8 va0_n = *(const bf16x8*)(hb + n0n + hi * 8 + lm * 4096);
    const bf16x8 va1_n = *(const bf16x8*)(hb + n0n + hi * 8 + lm * 4096 + 16);

    const f32x16 s = __builtin_amdgcn_mfma_f32_32x32x16_bf16(af_c, gf, zf16, 0, 0, 0);

    float rs = 0.f;
    unsigned w[8];
#pragma unroll
    for (int j = 0; j < 8; ++j) {
      const float pa = EXP2(s[2 * j]);
      const float pc = EXP2(s[2 * j + 1]);
      rs += pa + pc;
      w[j] = pk_bf16(pa, pc);
    }
    Lsum += rs;

    plane32_swap(w[0], w[2]);
    plane32_swap(w[1], w[3]);
    plane32_swap(w[4], w[6]);
    plane32_swap(w[5], w[7]);
    union { unsigned u[4]; bf16x8 v; } pb0, pb1;
    pb0.u[0] = w[0]; pb0.u[1] = w[1]; pb0.u[2] = w[2]; pb0.u[3] = w[3];
    pb1.u[0] = w[4]; pb1.u[1] = w[5]; pb1.u[2] = w[6]; pb1.u[3] = w[7];

    acc0 = __builtin_amdgcn_mfma_f32_32x32x16_bf16(va0_c, pb0.v, acc0, 0, 0, 0);
    acc0 = __builtin_amdgcn_mfma_f32_32x32x16_bf16(va1_c, pb1.v, acc0, 0, 0, 0);
    acc1 = __builtin_amdgcn_mfma_f32_32x32x16_bf16(va2_c, pb0.v, acc1, 0, 0, 0);
    acc1 = __builtin_amdgcn_mfma_f32_32x32x16_bf16(va3_c, pb1.v, acc1, 0, 0, 0);

    af_c = af_n; va0_c = va0_n; va1_c = va1_n;
  }

  // ---- cross-wave combine, 2-phase (17 KB LDS) ----
  const float Lfull = Lsum + __shfl_xor(Lsum, 32);
  lL[wv][l] = Lfull;
#pragma unroll
  for (int j = 0; j < 16; ++j) lacc[wv][j][l] = acc0[j];
  __syncthreads();

  const float Lg = lL[0][l] + lL[1][l] + lL[2][l] + lL[3][l];
  const float scale = gamma[0] / Lg;

  const float* xb = x + b * 64 * 4096;
  float* ob = out + b * 64 * 4096;

#pragma unroll
  for (int r = 0; r < 4; ++r) {  // phase A: acc0 rows -> channels 0..31
    const int j = wv * 4 + r;
    const float v = lacc[0][j][l] + lacc[1][j][l] + lacc[2][j][l] + lacc[3][j][l];
    const int c = (j & 3) + 8 * (j >> 2) + 4 * hi;
    const int idx = c * 4096 + m0 + lm;
    ob[idx] = fmaf(v, scale, xb[idx]);
  }
  __syncthreads();
#pragma unroll
  for (int j = 0; j < 16; ++j) lacc[wv][j][l] = acc1[j];
  __syncthreads();
#pragma unroll
  for (int r = 0; r < 4; ++r) {  // phase B: acc1 rows -> channels 32..63
    const int j = wv * 4 + r;
    const float v = lacc[0][j][l] + lacc[1][j][l] + lacc[2][j][l] + lacc[3][j][l];
    const int c = 32 + (j & 3) + 8 * (j >> 2) + 4 * hi;
    const int idx = c * 4096 + m0 + lm;
    ob[idx] = fmaf(v, scale, xb[idx]);
  }
}

extern "C" void kernel_launch(void* const* d_in, const int* in_sizes, int n_in,
                              void* d_out, int out_size, void* d_ws, size_t ws_size,
                              hipStream_t stream) {
  const float* x = (const float*)d_in[0];
  const float* Wq = (const float*)d_in[1];
  const float* bq = (const float*)d_in[2];
  const float* Wk = (const float*)d_in[3];
  const float* bk = (const float*)d_in[4];
  const float* Wv = (const float*)d_in[5];
  const float* bv = (const float*)d_in[6];
  const float* gamma = (const float*)d_in[7];
  float* out = (float*)d_out;

  __hip_bfloat16* ft = (__hip_bfloat16*)d_ws;          // [8][4096][16] (ext, 1 MB)
  __hip_bfloat16* gt = ft + 8 * 4096 * 16;             // [8][4096][8]  (0.5 MB)
  __hip_bfloat16* hv = gt + 8 * 4096 * 8;              // [8][64][4096] (4 MB)

  hipLaunchKernelGGL(proj_kernel, dim3(512), dim3(512), 0, stream,
                     x, Wq, bq, Wk, bk, Wv, bv, ft, gt, hv);
  hipLaunchKernelGGL(attn_kernel, dim3(1024), dim3(256), 0, stream,
                     ft, gt, hv, x, gamma, out);
}

// Round 12
// 123.400 us; speedup vs baseline: 1.4220x; 1.2102x over previous
//
#include <hip/hip_runtime.h>
#include <hip/hip_bf16.h>

// B=8, C=64, N=4096, CQK=8. Flash-attention with FIXED softmax offset:
//   s_out = log2e*(f.g) - 28.84 (offset in MFMA k=8 slot; cancels in norm)
//   p = exp2(s_out); beta = p/sum_n p; o = gamma*hv@beta + x
// ws: ft_ext [B][N][16] bf16 (0..7 = log2e*f, 8 = 1.0), gt [B][N][8], hv [B][64][N].

typedef __attribute__((ext_vector_type(16))) float f32x16;
typedef __attribute__((ext_vector_type(8))) short bf16x8;

#if __has_builtin(__builtin_amdgcn_exp2f)
#define EXP2(x) __builtin_amdgcn_exp2f(x)
#else
#define EXP2(x) exp2f(x)
#endif

__device__ __forceinline__ unsigned pk_bf16(float lo, float hi) {
  union { __hip_bfloat16 h; unsigned short u; } a, b;
  a.h = __float2bfloat16(lo); b.h = __float2bfloat16(hi);
  return (unsigned)a.u | ((unsigned)b.u << 16);
}

__device__ __forceinline__ void plane32_swap(unsigned& a, unsigned& b) {
  asm("v_permlane32_swap_b32 %0, %1" : "+v"(a), "+v"(b));
}

// ---------------- projection (UNCHANGED from r10 — control for the total-vs-attn gap) ----
__global__ __launch_bounds__(512) void proj_kernel(
    const float* __restrict__ x,
    const float* __restrict__ Wq, const float* __restrict__ bq,
    const float* __restrict__ Wk, const float* __restrict__ bk,
    const float* __restrict__ Wv, const float* __restrict__ bv,
    __hip_bfloat16* __restrict__ ft,
    __hip_bfloat16* __restrict__ gt,
    __hip_bfloat16* __restrict__ hv) {
  __shared__ float xs[64][65];
  const int t = threadIdx.x;
  const int p = t & 63;
  const int grp = t >> 6;
  const int b = blockIdx.x >> 6;
  const int n0 = (blockIdx.x & 63) << 6;

#pragma unroll
  for (int r = 0; r < 8; ++r) {
    const int c = grp * 8 + r;
    xs[c][p] = x[(b * 64 + c) * 4096 + n0 + p];
  }
  __syncthreads();

  float xcol[64];
#pragma unroll
  for (int c = 0; c < 64; ++c) xcol[c] = xs[c][p];

  const int o0 = __builtin_amdgcn_readfirstlane(grp);
  const int n = n0 + p;

  {
    float aq = bq[o0], ag = bk[o0];
#pragma unroll
    for (int c = 0; c < 64; ++c) {
      aq = fmaf(Wq[o0 * 64 + c], xcol[c], aq);
      ag = fmaf(Wk[o0 * 64 + c], xcol[c], ag);
    }
    ft[(b * 4096 + n) * 16 + o0] = __float2bfloat16(aq * 1.44269504f);
    gt[(b * 4096 + n) * 8 + o0] = __float2bfloat16(ag);
  }
  if (o0 == 0) {
    const bf16x8 fb = {(short)0x3F80, 0, 0, 0, 0, 0, 0, 0};
    *(bf16x8*)(ft + (b * 4096 + n) * 16 + 8) = fb;
  }
#pragma unroll
  for (int k = 0; k < 8; ++k) {
    const int o = o0 + 8 * k;
    float av = bv[o];
#pragma unroll
    for (int c = 0; c < 64; ++c) av = fmaf(Wv[o * 64 + c], xcol[c], av);
    hv[(b * 64 + o) * 4096 + n] = __float2bfloat16(av);
  }
}

// ---------------- fused flash attention: 64-query waves (V reuse x2) ----------------
// Block = (batch, 64-query tile), 512 thr = 8 waves; wave wv = keys [wv*512,+512), 16 iters.
// Per iter: af + va0..va3 loads feed TWO query sub-tiles (gf0,gf1): 2 QK + 8 PV MFMAs.
// QK D-frag: col m=l&31, row n=(j&3)+8*(j>>2)+4*(l>>5)  [HW-verified r2/r10]
// P->PV-B via v_permlane32_swap_b32 [HW-verified r2/r10]. 4-phase LDS split-K combine.
__global__ __launch_bounds__(512) void attn_kernel(
    const __hip_bfloat16* __restrict__ ft,
    const __hip_bfloat16* __restrict__ gt,
    const __hip_bfloat16* __restrict__ hv,
    const float* __restrict__ x,
    const float* __restrict__ gamma,
    float* __restrict__ out) {
  __shared__ float lacc[8][16][64];  // 32 KB, reused across 4 phases
  __shared__ float lL[8][2][64];     // 4 KB

  const int wv = threadIdx.x >> 6;   // 0..7 = key split
  const int l = threadIdx.x & 63;
  const int hi = l >> 5;
  const int lm = l & 31;
  const int bid = blockIdx.x;                      // 512 blocks
  const int swz = ((bid & 7) << 6) + (bid >> 3);   // bijective: 512 % 8 == 0
  const int b = swz >> 6;                          // batch == XCD
  const int m0 = (swz & 63) << 6;                  // 64-query tile base

  const __hip_bfloat16* ftb = ft + b * 4096 * 16;
  const __hip_bfloat16* gtb = gt + b * 4096 * 8;
  const __hip_bfloat16* hb = hv + b * 64 * 4096;

  f32x16 zf16;
#pragma unroll
  for (int j = 0; j < 16; ++j) zf16[j] = 0.f;

  // Q fragments: lanes<32 carry k=0..7 (=q) of col m0+qt*32+lm; lanes>=32 carry k=8 offset
  bf16x8 gf0 = {(short)0xC1E7, 0, 0, 0, 0, 0, 0, 0};  // -28.84 at k=8
  bf16x8 gf1 = gf0;
  if (l < 32) {
    gf0 = *(const bf16x8*)(gtb + (m0 + lm) * 8);
    gf1 = *(const bf16x8*)(gtb + (m0 + 32 + lm) * 8);
  }

  f32x16 acc00 = zf16, acc01 = zf16, acc10 = zf16, acc11 = zf16;  // [ct][qt]
  float Lsum0 = 0.f, Lsum1 = 0.f;

  const int kb = wv << 9;  // wave key base (512 keys)
  for (int it = 0; it < 16; ++it) {
    const int n0 = kb + (it << 5);

    const bf16x8 af = *(const bf16x8*)(ftb + (n0 + lm) * 16 + hi * 8);

    // ---- q-sub-tile 0 ----
    union { unsigned u[4]; bf16x8 v; } pb00, pb01, pb10, pb11;
    {
      const f32x16 s = __builtin_amdgcn_mfma_f32_32x32x16_bf16(af, gf0, zf16, 0, 0, 0);
      float rs = 0.f;
      unsigned w[8];
#pragma unroll
      for (int j = 0; j < 8; ++j) {
        const float pa = EXP2(s[2 * j]);
        const float pc = EXP2(s[2 * j + 1]);
        rs += pa + pc;
        w[j] = pk_bf16(pa, pc);
      }
      Lsum0 += rs;
      plane32_swap(w[0], w[2]); plane32_swap(w[1], w[3]);
      plane32_swap(w[4], w[6]); plane32_swap(w[5], w[7]);
      pb00.u[0] = w[0]; pb00.u[1] = w[1]; pb00.u[2] = w[2]; pb00.u[3] = w[3];
      pb01.u[0] = w[4]; pb01.u[1] = w[5]; pb01.u[2] = w[6]; pb01.u[3] = w[7];
    }
    // ---- q-sub-tile 1 ----
    {
      const f32x16 s = __builtin_amdgcn_mfma_f32_32x32x16_bf16(af, gf1, zf16, 0, 0, 0);
      float rs = 0.f;
      unsigned w[8];
#pragma unroll
      for (int j = 0; j < 8; ++j) {
        const float pa = EXP2(s[2 * j]);
        const float pc = EXP2(s[2 * j + 1]);
        rs += pa + pc;
        w[j] = pk_bf16(pa, pc);
      }
      Lsum1 += rs;
      plane32_swap(w[0], w[2]); plane32_swap(w[1], w[3]);
      plane32_swap(w[4], w[6]); plane32_swap(w[5], w[7]);
      pb10.u[0] = w[0]; pb10.u[1] = w[1]; pb10.u[2] = w[2]; pb10.u[3] = w[3];
      pb11.u[0] = w[4]; pb11.u[1] = w[5]; pb11.u[2] = w[6]; pb11.u[3] = w[7];
    }

    // ---- PV: channel tile 0 then 1; va loads shared by both q-sub-tiles ----
    const __hip_bfloat16* hp = hb + n0 + hi * 8;
    {
      const bf16x8 va0 = *(const bf16x8*)(hp + lm * 4096);
      const bf16x8 va1 = *(const bf16x8*)(hp + lm * 4096 + 16);
      acc00 = __builtin_amdgcn_mfma_f32_32x32x16_bf16(va0, pb00.v, acc00, 0, 0, 0);
      acc00 = __builtin_amdgcn_mfma_f32_32x32x16_bf16(va1, pb01.v, acc00, 0, 0, 0);
      acc01 = __builtin_amdgcn_mfma_f32_32x32x16_bf16(va0, pb10.v, acc01, 0, 0, 0);
      acc01 = __builtin_amdgcn_mfma_f32_32x32x16_bf16(va1, pb11.v, acc01, 0, 0, 0);
    }
    {
      const bf16x8 va2 = *(const bf16x8*)(hp + (32 + lm) * 4096);
      const bf16x8 va3 = *(const bf16x8*)(hp + (32 + lm) * 4096 + 16);
      acc10 = __builtin_amdgcn_mfma_f32_32x32x16_bf16(va2, pb00.v, acc10, 0, 0, 0);
      acc10 = __builtin_amdgcn_mfma_f32_32x32x16_bf16(va3, pb01.v, acc10, 0, 0, 0);
      acc11 = __builtin_amdgcn_mfma_f32_32x32x16_bf16(va2, pb10.v, acc11, 0, 0, 0);
      acc11 = __builtin_amdgcn_mfma_f32_32x32x16_bf16(va3, pb11.v, acc11, 0, 0, 0);
    }
  }

  // ---- cross-wave split-K combine, 4 phases ----
  Lsum0 += __shfl_xor(Lsum0, 32);
  Lsum1 += __shfl_xor(Lsum1, 32);
  lL[wv][0][l] = Lsum0;
  lL[wv][1][l] = Lsum1;

  const float* xb = x + b * 64 * 4096;
  float* ob = out + b * 64 * 4096;
  const float gm = gamma[0];
  float scale0, scale1;

#pragma unroll
  for (int ph = 0; ph < 4; ++ph) {  // ph = ct*2 + qt
    const f32x16& a = (ph == 0) ? acc00 : (ph == 1) ? acc01 : (ph == 2) ? acc10 : acc11;
#pragma unroll
    for (int j = 0; j < 16; ++j) lacc[wv][j][l] = a[j];
    __syncthreads();
    if (ph == 0) {  // lL is ready after the first barrier
      float Lg0 = 0.f, Lg1 = 0.f;
#pragma unroll
      for (int ww = 0; ww < 8; ++ww) { Lg0 += lL[ww][0][l]; Lg1 += lL[ww][1][l]; }
      scale0 = gm / Lg0;
      scale1 = gm / Lg1;
    }
    const int ct = ph >> 1;
    const int qt = ph & 1;
    const float sc = qt ? scale1 : scale0;
#pragma unroll
    for (int r = 0; r < 2; ++r) {
      const int j = wv * 2 + r;
      float v = 0.f;
#pragma unroll
      for (int ww = 0; ww < 8; ++ww) v += lacc[ww][j][l];
      const int c = ct * 32 + (j & 3) + 8 * (j >> 2) + 4 * hi;
      const int idx = c * 4096 + m0 + qt * 32 + lm;
      ob[idx] = fmaf(v, sc, xb[idx]);
    }
    __syncthreads();
  }
}

extern "C" void kernel_launch(void* const* d_in, const int* in_sizes, int n_in,
                              void* d_out, int out_size, void* d_ws, size_t ws_size,
                              hipStream_t stream) {
  const float* x = (const float*)d_in[0];
  const float* Wq = (const float*)d_in[1];
  const float* bq = (const float*)d_in[2];
  const float* Wk = (const float*)d_in[3];
  const float* bk = (const float*)d_in[4];
  const float* Wv = (const float*)d_in[5];
  const float* bv = (const float*)d_in[6];
  const float* gamma = (const float*)d_in[7];
  float* out = (float*)d_out;

  __hip_bfloat16* ft = (__hip_bfloat16*)d_ws;          // [8][4096][16] (1 MB)
  __hip_bfloat16* gt = ft + 8 * 4096 * 16;             // [8][4096][8]  (0.5 MB)
  __hip_bfloat16* hv = gt + 8 * 4096 * 8;              // [8][64][4096] (4 MB)

  hipLaunchKernelGGL(proj_kernel, dim3(512), dim3(512), 0, stream,
                     x, Wq, bq, Wk, bk, Wv, bv, ft, gt, hv);
  hipLaunchKernelGGL(attn_kernel, dim3(512), dim3(512), 0, stream,
                     ft, gt, hv, x, gamma, out);
}